// Round 7
// baseline (140.535 us; speedup 1.0000x reference)
//
#include <hip/hip_runtime.h>
#include <math.h>

#define BB 1024
#define DD 128
#define QQ 65536
#define THREADS 256
#define NSLICES 256
#define SROWS (QQ / NSLICES)      // 256 rows per slice
#define STEPS (SROWS / 16)        // 16 steps per wave
#define INV_T 14.285714285714286f
#define SCALE 20.609929155556627f   // (1/T) * log2(e)
#define LN2F 0.6931471805599453f

typedef short short8 __attribute__((ext_vector_type(8)));
typedef float f32x4  __attribute__((ext_vector_type(4)));
typedef unsigned short us4 __attribute__((ext_vector_type(4)));

static __device__ __forceinline__ unsigned short bf16rne(float f) {
    union { float f; unsigned u; } v; v.f = f;
    unsigned r = (v.u + 0x7FFFu + ((v.u >> 16) & 1u)) >> 16;
    return (unsigned short)r;
}

static __device__ __forceinline__ short8 pack8s(float4 x, float4 y) { // scaled
    short8 r;
    r[0]=(short)bf16rne(x.x*SCALE); r[1]=(short)bf16rne(x.y*SCALE);
    r[2]=(short)bf16rne(x.z*SCALE); r[3]=(short)bf16rne(x.w*SCALE);
    r[4]=(short)bf16rne(y.x*SCALE); r[5]=(short)bf16rne(y.y*SCALE);
    r[6]=(short)bf16rne(y.z*SCALE); r[7]=(short)bf16rne(y.w*SCALE);
    return r;
}
static __device__ __forceinline__ short8 pack8(float4 x, float4 y) { // unscaled
    short8 r;
    r[0]=(short)bf16rne(x.x); r[1]=(short)bf16rne(x.y);
    r[2]=(short)bf16rne(x.z); r[3]=(short)bf16rne(x.w);
    r[4]=(short)bf16rne(y.x); r[5]=(short)bf16rne(y.y);
    r[6]=(short)bf16rne(y.z); r[7]=(short)bf16rne(y.w);
    return r;
}

// ---------- prep: qbf convert + qlabn + cnt histogram + srr + f2bf ----------
// blocks 0..511: convert queue_new -> qbf (blocks 0..255 also labels/histogram);
// blocks 512..515: srr dot + f2bf (scaled bf16 of f2), one thread per batch row.
template<int PRE>
__global__ __launch_bounds__(256)
void k_prep(const float* __restrict__ features, const int* __restrict__ labels,
            const float* __restrict__ queue, const int* __restrict__ queue_labels,
            unsigned short* __restrict__ qbf, int* __restrict__ qlabn,
            unsigned short* __restrict__ f2bf,
            int* __restrict__ cnt, float* __restrict__ srr)
{
    const int bid = blockIdx.x;
    const int t = bid * 256 + threadIdx.x;
    if (bid < 512) {
        if (PRE) {
#pragma unroll
            for (int k = 0; k < 16; ++k) {
                int u = k * 131072 + t;          // us4 index
                int e = u * 4;                   // element index
                int row = e >> 7;
                const float* src = (row < BB)
                    ? (features + (size_t)row * 2 * DD + (e & 127))
                    : (queue + ((size_t)e - (size_t)BB * DD));
                float4 v = *reinterpret_cast<const float4*>(src);
                us4 pk;
                pk[0] = bf16rne(v.x); pk[1] = bf16rne(v.y);
                pk[2] = bf16rne(v.z); pk[3] = bf16rne(v.w);
                *reinterpret_cast<us4*>(qbf + (size_t)e) = pk;
            }
        }
        if (bid < 256) {
            int lab = (t < BB) ? labels[t] : queue_labels[t - BB];
            if (PRE) qlabn[t] = lab;
            atomicAdd(&cnt[lab], 1);
        }
    } else {
        int r = t - 512 * 256;                   // 0..1023
        const float* f2p = features + (size_t)r * 2 * DD + DD;
        const float* f1p = features + (size_t)r * 2 * DD;
        float d = 0.f;
#pragma unroll
        for (int k = 0; k < DD / 8; ++k) {
            float4 a0 = reinterpret_cast<const float4*>(f2p)[2 * k];
            float4 a1 = reinterpret_cast<const float4*>(f2p)[2 * k + 1];
            float4 b0 = reinterpret_cast<const float4*>(f1p)[2 * k];
            float4 b1 = reinterpret_cast<const float4*>(f1p)[2 * k + 1];
            d += a0.x * b0.x + a0.y * b0.y + a0.z * b0.z + a0.w * b0.w;
            d += a1.x * b1.x + a1.y * b1.y + a1.z * b1.z + a1.w * b1.w;
            if (PRE)
                *reinterpret_cast<short8*>(f2bf + (size_t)r * DD + k * 8) = pack8s(a0, a1);
        }
        srr[r] = d;
    }
}

// ---------- main: no LDS, no barriers; direct global->reg MFMA ----------
// grid: 8 colgroups x 256 slices; block = 4 waves = 128 cols over one slice;
// wave = 32 cols (2 x 16-col B frags) x SROWS queue rows.
template<int PRE>
__global__ __launch_bounds__(THREADS)
void supcon_main(const float* __restrict__ features, const int* __restrict__ labels,
                 const float* __restrict__ queue, const int* __restrict__ queue_labels,
                 const unsigned short* __restrict__ qbf, const int* __restrict__ qlabn,
                 const unsigned short* __restrict__ f2bf,
                 float* __restrict__ rowacc)
{
    const int tid = threadIdx.x;
    const int l = tid & 63, w = tid >> 6;
    const int bid = blockIdx.x;
    const int slice = bid & (NSLICES - 1);       // bid%8==slice%8 -> slice pinned to one XCD
    const int cg = bid >> 8;
    const int colbase = cg * 128 + w * 32;
    const int laneRow = l & 15, laneSeg = l >> 4;

    // stationary B: 2x16 f2 cols, pre-scaled bf16
    short8 bf0[4], bf1[4];
    int mylab[2];
    {
        int r0 = colbase + laneRow, r1 = colbase + 16 + laneRow;
        mylab[0] = labels[r0]; mylab[1] = labels[r1];
        if (PRE) {
            const unsigned short* p0 = f2bf + (size_t)r0 * DD + laneSeg * 8;
            const unsigned short* p1 = f2bf + (size_t)r1 * DD + laneSeg * 8;
#pragma unroll
            for (int kk = 0; kk < 4; ++kk) {
                bf0[kk] = *reinterpret_cast<const short8*>(p0 + kk * 32);
                bf1[kk] = *reinterpret_cast<const short8*>(p1 + kk * 32);
            }
        } else {
            const float* p0 = features + (size_t)r0 * 2 * DD + DD + laneSeg * 8;
            const float* p1 = features + (size_t)r1 * 2 * DD + DD + laneSeg * 8;
#pragma unroll
            for (int kk = 0; kk < 4; ++kk) {
                bf0[kk] = pack8s(*reinterpret_cast<const float4*>(p0 + kk * 32),
                                 *reinterpret_cast<const float4*>(p0 + kk * 32 + 4));
                bf1[kk] = pack8s(*reinterpret_cast<const float4*>(p1 + kk * 32),
                                 *reinterpret_cast<const float4*>(p1 + kk * 32 + 4));
            }
        }
    }

    float tot0 = 0.f, tot1 = 0.f, pose0 = 0.f, pose1 = 0.f, psum0 = 0.f, psum1 = 0.f;

    const int jbase = slice * SROWS;

#pragma unroll 2
    for (int c = 0; c < STEPS; ++c) {
        const int j0 = jbase + c * 16;
        short8 a0, a1, a2, a3;
        if (PRE) {
            const unsigned short* ap = qbf + (size_t)(j0 + laneRow) * DD + laneSeg * 8;
            a0 = *reinterpret_cast<const short8*>(ap);
            a1 = *reinterpret_cast<const short8*>(ap + 32);
            a2 = *reinterpret_cast<const short8*>(ap + 64);
            a3 = *reinterpret_cast<const short8*>(ap + 96);
        } else {
            int j = j0 + laneRow;
            const float* src = ((j < BB) ? (features + (size_t)j * 2 * DD)
                                         : (queue + (size_t)(j - BB) * DD)) + laneSeg * 8;
            a0 = pack8(*reinterpret_cast<const float4*>(src),
                       *reinterpret_cast<const float4*>(src + 4));
            a1 = pack8(*reinterpret_cast<const float4*>(src + 32),
                       *reinterpret_cast<const float4*>(src + 36));
            a2 = pack8(*reinterpret_cast<const float4*>(src + 64),
                       *reinterpret_cast<const float4*>(src + 68));
            a3 = pack8(*reinterpret_cast<const float4*>(src + 96),
                       *reinterpret_cast<const float4*>(src + 100));
        }

        int4 ql4;
        if (PRE) ql4 = *reinterpret_cast<const int4*>(qlabn + j0 + (laneSeg << 2));
        else {
            int j = j0 + (laneSeg << 2);
            ql4 = (j < BB) ? *reinterpret_cast<const int4*>(labels + j)
                           : *reinterpret_cast<const int4*>(queue_labels + (j - BB));
        }
        const int* ql = reinterpret_cast<const int*>(&ql4);

        f32x4 acc0 = {0.f,0.f,0.f,0.f}, acc1 = {0.f,0.f,0.f,0.f};
        acc0 = __builtin_amdgcn_mfma_f32_16x16x32_bf16(a0, bf0[0], acc0, 0, 0, 0);
        acc1 = __builtin_amdgcn_mfma_f32_16x16x32_bf16(a0, bf1[0], acc1, 0, 0, 0);
        acc0 = __builtin_amdgcn_mfma_f32_16x16x32_bf16(a1, bf0[1], acc0, 0, 0, 0);
        acc1 = __builtin_amdgcn_mfma_f32_16x16x32_bf16(a1, bf1[1], acc1, 0, 0, 0);
        acc0 = __builtin_amdgcn_mfma_f32_16x16x32_bf16(a2, bf0[2], acc0, 0, 0, 0);
        acc1 = __builtin_amdgcn_mfma_f32_16x16x32_bf16(a2, bf1[2], acc1, 0, 0, 0);
        acc0 = __builtin_amdgcn_mfma_f32_16x16x32_bf16(a3, bf0[3], acc0, 0, 0, 0);
        acc1 = __builtin_amdgcn_mfma_f32_16x16x32_bf16(a3, bf1[3], acc1, 0, 0, 0);

#pragma unroll
        for (int reg = 0; reg < 4; ++reg) {
            float aa = acc0[reg];
            float e  = exp2f(aa);                 // aa = s * log2(e)
            float pf = (ql[reg] == mylab[0]) ? 1.0f : 0.0f;
            tot0 += e;
            pose0 = fmaf(pf, e, pose0);
            psum0 = fmaf(pf, aa, psum0);
            float ab = acc1[reg];
            float eb = exp2f(ab);
            float pg = (ql[reg] == mylab[1]) ? 1.0f : 0.0f;
            tot1 += eb;
            pose1 = fmaf(pg, eb, pose1);
            psum1 = fmaf(pg, ab, psum1);
        }
    }

    // reduce across the 4 lane-groups sharing each output col
#pragma unroll
    for (int off = 16; off <= 32; off <<= 1) {
        tot0  += __shfl_xor(tot0,  off);
        pose0 += __shfl_xor(pose0, off);
        psum0 += __shfl_xor(psum0, off);
        tot1  += __shfl_xor(tot1,  off);
        pose1 += __shfl_xor(pose1, off);
        psum1 += __shfl_xor(psum1, off);
    }
    if (l < 16) {
        float* d0 = rowacc + (size_t)(colbase + l) * 4;
        atomicAdd(d0 + 0, tot0);
        atomicAdd(d0 + 1, pose0);
        atomicAdd(d0 + 2, psum0);
        float* d1 = rowacc + (size_t)(colbase + 16 + l) * 4;
        atomicAdd(d1 + 0, tot1);
        atomicAdd(d1 + 1, pose1);
        atomicAdd(d1 + 2, psum1);
    }
}

// ---------- finish: per-row log terms, two scalars, last block writes out ----------
__global__ __launch_bounds__(256)
void f_finish(const float* __restrict__ rowacc, const float* __restrict__ srr,
              const int* __restrict__ cnt, const int* __restrict__ labels,
              float* __restrict__ scal, int* __restrict__ ticket,
              float* __restrict__ out)
{
    __shared__ float red[4][2];
    const int r = blockIdx.x * 256 + threadIdx.x;
    const int wv = threadIdx.x >> 6, lane = threadIdx.x & 63;

    float4 v = reinterpret_cast<const float4*>(rowacc)[r];
    float tot = v.x, pose = v.y, ps = v.z;
    float srow = srr[r] * INV_T;                 // exact diag logit
    float trip = srow - logf(tot - expf(srow));
    float wgt  = 1.f / (float)(cnt[labels[r]] - 1);
    float mlpp = (ps * LN2F - srow) * wgt - logf(tot - pose);

#pragma unroll
    for (int off = 32; off > 0; off >>= 1) {
        trip += __shfl_xor(trip, off);
        mlpp += __shfl_xor(mlpp, off);
    }
    if (lane == 0) { red[wv][0] = trip; red[wv][1] = mlpp; }
    __syncthreads();
    if (threadIdx.x == 0) {
        atomicAdd(&scal[0], red[0][0] + red[1][0] + red[2][0] + red[3][0]);
        atomicAdd(&scal[1], red[0][1] + red[1][1] + red[2][1] + red[3][1]);
        __threadfence();
        int old = atomicAdd(ticket, 1);
        if (old == 3) {
            float aT = atomicAdd(&scal[0], 0.f);
            float aM = atomicAdd(&scal[1], 0.f);
            float selfl  = -aT / (float)BB;
            float classl = -aM / (float)BB;
            out[0] = 0.5f * (selfl + classl);
            out[1] = selfl;
            out[2] = classl;
        }
    }
}

extern "C" void kernel_launch(void* const* d_in, const int* in_sizes, int n_in,
                              void* d_out, int out_size, void* d_ws, size_t ws_size,
                              hipStream_t stream)
{
    const float* features     = (const float*)d_in[0];
    const int*   labels       = (const int*)  d_in[1];
    const float* queue        = (const float*)d_in[2];
    const int*   queue_labels = (const int*)  d_in[3];
    char* ws = (char*)d_ws;

    // ws layout: [zeroed: cnt 4096 | scal 128 | ticket 128 | rowacc 16384]
    //            srr 4096 | f2bf 256KB | qbf 16MB | qlabn 256KB
    const size_t cnt_off    = 0;
    const size_t scal_off   = 4096;
    const size_t ticket_off = 4096 + 128;
    const size_t rowacc_off = 4096 + 256;
    const size_t zero_sz    = rowacc_off + 16384;
    const size_t srr_off    = zero_sz;
    const size_t f2bf_off   = srr_off + 4096;
    const size_t f2bf_sz    = (size_t)BB * DD * 2;        // 256 KB
    const size_t qbf_off    = f2bf_off + f2bf_sz;
    const size_t qbf_sz     = (size_t)QQ * DD * 2;        // 16 MB
    const size_t qlabn_off  = qbf_off + qbf_sz;
    const size_t total_pre  = qlabn_off + (size_t)QQ * 4;

    const bool pre = ws_size >= total_pre;

    int*   cnt    = (int*)(ws + cnt_off);
    float* scal   = (float*)(ws + scal_off);
    int*   ticket = (int*)(ws + ticket_off);
    float* rowacc = (float*)(ws + rowacc_off);
    float* srr    = (float*)(ws + srr_off);
    unsigned short* f2bf = pre ? (unsigned short*)(ws + f2bf_off) : nullptr;
    unsigned short* qbf  = pre ? (unsigned short*)(ws + qbf_off) : nullptr;
    int* qlabn           = pre ? (int*)(ws + qlabn_off) : nullptr;

    hipMemsetAsync(ws, 0, zero_sz, stream);

    if (pre)
        k_prep<1><<<dim3(516), dim3(256), 0, stream>>>(
            features, labels, queue, queue_labels, qbf, qlabn, f2bf, cnt, srr);
    else
        k_prep<0><<<dim3(516), dim3(256), 0, stream>>>(
            features, labels, queue, queue_labels, qbf, qlabn, f2bf, cnt, srr);

    dim3 grid(8 * NSLICES);     // 2048 blocks: cg*256 + slice
    if (pre)
        supcon_main<1><<<grid, dim3(THREADS), 0, stream>>>(
            features, labels, queue, queue_labels, qbf, qlabn, f2bf, rowacc);
    else
        supcon_main<0><<<grid, dim3(THREADS), 0, stream>>>(
            features, labels, queue, queue_labels, qbf, qlabn, f2bf, rowacc);

    f_finish<<<dim3(4), dim3(256), 0, stream>>>(
        rowacc, srr, cnt, labels, scal, ticket, (float*)d_out);
}